// Round 4
// baseline (588.585 us; speedup 1.0000x reference)
//
#include <hip/hip_runtime.h>

// Problem constants (match reference)
constexpr int U_N = 100000;   // users
constexpr int I_N = 100000;   // items
constexpr int D   = 64;       // latent dim
constexpr int NL  = 3;        // layers
constexpr int NN  = U_N + I_N;              // 200000 nodes
constexpr long long NDLL = (long long)NN * D;
constexpr long long ND4  = NDLL / 4;
constexpr long long UD4  = (long long)U_N * D / 4;

// Bucket sort parameters: bucket = row >> 10  (1024 rows per bucket).
constexpr int BKT_SHIFT = 10;
constexpr int BKT_W     = 1024;                     // rows per bucket
constexpr int NBKT      = (NN + BKT_W - 1) / BKT_W; // 196
// Fused scatter: 1024-thread blocks, <=13 staged edges per thread.
constexpr int KSTAGE    = 13;
constexpr int SCHUNK_MAX = KSTAGE * 1024;           // 13312
// Degree-permutation histogram bins (degree clamped to 1023)
constexpr int DBINS     = 1024;

typedef float f32x2 __attribute__((ext_vector_type(2)));

__device__ __forceinline__ float sigmoidf_(float x) {
    return 1.0f / (1.0f + expf(-x));
}

__device__ __forceinline__ float bf_lo(unsigned int u) {
    return __uint_as_float(u << 16);
}
__device__ __forceinline__ float bf_hi(unsigned int u) {
    return __uint_as_float(u & 0xFFFF0000u);
}
// unpack a packed bf16 pair into a float2 (dims 2k, 2k+1)
__device__ __forceinline__ f32x2 bfpair(unsigned int u) {
    f32x2 r;
    r.x = __uint_as_float(u << 16);
    r.y = __uint_as_float(u & 0xFFFF0000u);
    return r;
}
__device__ __forceinline__ unsigned short f2bf(float f) {
    unsigned int u = __float_as_uint(f);
    u += 0x7FFFu + ((u >> 16) & 1u);   // round-to-nearest-even
    return (unsigned short)(u >> 16);
}
__device__ __forceinline__ unsigned int pack2bf(float lo, float hi) {
    return (unsigned int)f2bf(lo) | ((unsigned int)f2bf(hi) << 16);
}

// ---------------------------------------------------------------------------
// Layer-0 fusion: e0b(bf16) = fused emb (gather source for layer 1).
// ---------------------------------------------------------------------------
__global__ void fuse0_bf16_kernel(const float* __restrict__ user_emb,
                                  const float* __restrict__ item_emb,
                                  const float* __restrict__ symptom_emb,
                                  const float* __restrict__ herb_emb,
                                  const float* __restrict__ user_lw,
                                  const float* __restrict__ item_lw,
                                  unsigned short* __restrict__ e0b) {
    long long idx = (long long)blockIdx.x * blockDim.x + threadIdx.x;
    if (idx >= ND4) return;
    float a0 = sigmoidf_(user_lw[0]);
    float b0 = sigmoidf_(item_lw[0]);
    float4 e, s;
    float w;
    if (idx < UD4) {
        e = ((const float4*)user_emb)[idx];
        s = ((const float4*)symptom_emb)[idx];
        w = a0;
    } else {
        long long j = idx - UD4;
        e = ((const float4*)item_emb)[j];
        s = ((const float4*)herb_emb)[j];
        w = b0;
    }
    ushort4 rb;
    rb.x = f2bf(w * e.x + (1.0f - w) * s.x);
    rb.y = f2bf(w * e.y + (1.0f - w) * s.y);
    rb.z = f2bf(w * e.z + (1.0f - w) * s.z);
    rb.w = f2bf(w * e.w + (1.0f - w) * s.w);
    ((ushort4*)e0b)[idx] = rb;
}

// ---------------------------------------------------------------------------
// CSR build, slab layout: bucket b owns slab [b*cap, b*cap + cnt_b) in both
// binned and sorted. Cursor init -> fused count+scatter -> per-bucket CSR.
// ---------------------------------------------------------------------------
__global__ void init_cursor_kernel(int* __restrict__ cursor, int cap) {
    int i = blockIdx.x * blockDim.x + threadIdx.x;
    if (i < NBKT) cursor[i] = i * cap;
}

// Fused hist+reserve+scatter: reads (val,row,col) exactly once, stages them
// in registers (statically indexed via full unroll), counts into LDS hist,
// reserves one global-atomic slab range per (block,bucket), scatters.
__global__ void fused_scatter_kernel(const float* __restrict__ edge_val,
                                     const int*   __restrict__ edge_row,
                                     const int*   __restrict__ edge_col,
                                     int* __restrict__ cursor,
                                     int2* __restrict__ binned,
                                     int E, int chunk) {
    __shared__ int h[NBKT];
    int tid = threadIdx.x;
    if (tid < NBKT) h[tid] = 0;
    __syncthreads();
    int s_ = blockIdx.x * chunk;
    int eend = min(E, s_ + chunk);
    int rr[KSTAGE];
    int cc[KSTAGE];
    float vv[KSTAGE];
    #pragma unroll
    for (int k = 0; k < KSTAGE; ++k) {
        int e = s_ + tid + k * 1024;
        bool ok = e < eend;
        rr[k] = ok ? edge_row[e] : -1;
        cc[k] = ok ? edge_col[e] : 0;
        vv[k] = ok ? edge_val[e] : 0.0f;
        if (ok) atomicAdd(&h[rr[k] >> BKT_SHIFT], 1);
    }
    __syncthreads();
    if (tid < NBKT) {
        int c = h[tid];
        if (c) h[tid] = atomicAdd(&cursor[tid], c);
    }
    __syncthreads();
    #pragma unroll
    for (int k = 0; k < KSTAGE; ++k) {
        if (rr[k] >= 0) {
            int b = rr[k] >> BKT_SHIFT;
            int pos = atomicAdd(&h[b], 1);
            binned[pos] = make_int2(__float_as_int(vv[k]),
                                    cc[k] | ((rr[k] & (BKT_W - 1)) << 18));
        }
    }
}

// Per-bucket CSR: one 1024-thread block per bucket -> row_ptr2 (start,end)
// + row-sorted slab. sorted.y stores col<<7 (byte offset of 128 B source
// row) so the spmm gather address is a single OR with the lane's oct offset.
__global__ void bucket_to_csr_kernel(const int2* __restrict__ binned,
                                     const int*  __restrict__ cursor,
                                     int2* __restrict__ row_ptr2,
                                     int2* __restrict__ sorted, int cap) {
    int b = blockIdx.x;
    int start = b * cap;
    int end   = cursor[b];           // start + cnt_b after fused_scatter
    __shared__ int rc[BKT_W];
    __shared__ int sm[BKT_W];
    int tid = threadIdx.x;            // blockDim.x == BKT_W == 1024
    rc[tid] = 0;
    __syncthreads();
    for (int e = start + tid; e < end; e += blockDim.x)
        atomicAdd(&rc[(unsigned)binned[e].y >> 18], 1);
    __syncthreads();
    int x = rc[tid];
    sm[tid] = x;
    __syncthreads();
    for (int off = 1; off < BKT_W; off <<= 1) {
        int t = (tid >= off) ? sm[tid - off] : 0;
        __syncthreads();
        sm[tid] += t;
        __syncthreads();
    }
    int excl = sm[tid] - x;
    int gidx = (b << BKT_SHIFT) + tid;
    if (gidx < NN) row_ptr2[gidx] = make_int2(start + excl, start + excl + x);
    __syncthreads();
    rc[tid] = excl;
    __syncthreads();
    for (int e = start + tid; e < end; e += blockDim.x) {
        int2 a = binned[e];
        int rl = (unsigned)a.y >> 18;
        int pos = start + atomicAdd(&rc[rl], 1);
        sorted[pos] = make_int2(a.x, (a.y & 0x3FFFF) << 7);
    }
}

// ---------------------------------------------------------------------------
// Degree-balanced row permutation (LPT): counting sort of rows by DESCENDING
// degree. Waves then process 8 equal-degree rows -> no exec-mask waste from
// Poisson trip-count divergence, and heavy rows dispatch first.
// ---------------------------------------------------------------------------
__global__ void zero_hist_kernel(int* __restrict__ hist) {
    hist[threadIdx.x] = 0;            // <<<1, DBINS>>>
}

__global__ void deg_hist_kernel(const int2* __restrict__ row_ptr2,
                                int* __restrict__ hist) {
    __shared__ int h[DBINS];
    int tid = threadIdx.x;            // 1024
    h[tid] = 0;
    __syncthreads();
    int i = blockIdx.x * 1024 + tid;
    if (i < NN) {
        int2 rp = row_ptr2[i];
        int d = min(rp.y - rp.x, DBINS - 1);
        atomicAdd(&h[DBINS - 1 - d], 1);   // descending degree
    }
    __syncthreads();
    int c = h[tid];
    if (c) atomicAdd(&hist[tid], c);
}

__global__ void scan_hist_kernel(const int* __restrict__ hist,
                                 int* __restrict__ cur) {
    __shared__ int sm[DBINS];
    int tid = threadIdx.x;            // 1024
    int x = hist[tid];
    sm[tid] = x;
    __syncthreads();
    for (int off = 1; off < DBINS; off <<= 1) {
        int t = (tid >= off) ? sm[tid - off] : 0;
        __syncthreads();
        sm[tid] += t;
        __syncthreads();
    }
    cur[tid] = sm[tid] - x;           // exclusive
}

__global__ void perm_scatter_kernel(const int2* __restrict__ row_ptr2,
                                    int* __restrict__ cur,
                                    int* __restrict__ perm) {
    __shared__ int h[DBINS];
    __shared__ int base_[DBINS];
    int tid = threadIdx.x;            // 1024
    h[tid] = 0;
    __syncthreads();
    int i = blockIdx.x * 1024 + tid;
    int bin = -1;
    if (i < NN) {
        int2 rp = row_ptr2[i];
        int d = min(rp.y - rp.x, DBINS - 1);
        bin = DBINS - 1 - d;
        atomicAdd(&h[bin], 1);
    }
    __syncthreads();
    int c = h[tid];
    base_[tid] = c ? atomicAdd(&cur[tid], c) : 0;
    h[tid] = 0;
    __syncthreads();
    if (i < NN) {
        int loc = atomicAdd(&h[bin], 1);
        perm[base_[bin] + loc] = i;
    }
}

// ---------------------------------------------------------------------------
// Core CSR row accumulation, 8-rows-per-wave layout: lane = (r,p):
// r = row-in-group (8), p = dim oct (8). Each 8-lane group sequentially
// accumulates its own row (no cross-lane reduce).
// Unroll-8 + software pipeline: gathers for block i overlap the sorted
// loads for block i+1. Tail = single masked 8-wide block.
// sorted.y is pre-shifted col<<7; gather byte addr = y | (p<<4).
// ---------------------------------------------------------------------------
__device__ __forceinline__ void csr_row_sum8(const int2* __restrict__ sorted,
                                             const char* __restrict__ srcB,
                                             int start, int end, unsigned poff,
                                             f32x2 s[4]) {
    #pragma unroll
    for (int j = 0; j < 4; ++j) s[j] = (f32x2){0.f, 0.f};
    int e = start;
    if (e + 8 <= end) {
        int2 a[8];
        #pragma unroll
        for (int k = 0; k < 8; ++k) a[k] = sorted[e + k];
        // steady state: gathers(i) || sorted-loads(i+1)
        for (; e + 16 <= end; e += 8) {
            uint4 q[8];
            #pragma unroll
            for (int k = 0; k < 8; ++k)
                q[k] = *(const uint4*)(srcB + (size_t)((unsigned)a[k].y | poff));
            int2 an[8];
            #pragma unroll
            for (int k = 0; k < 8; ++k) an[k] = sorted[e + 8 + k];
            #pragma unroll
            for (int k = 0; k < 8; ++k) {
                f32x2 v; v.x = __int_as_float(a[k].x); v.y = v.x;
                s[0] += v * bfpair(q[k].x);
                s[1] += v * bfpair(q[k].y);
                s[2] += v * bfpair(q[k].z);
                s[3] += v * bfpair(q[k].w);
            }
            #pragma unroll
            for (int k = 0; k < 8; ++k) a[k] = an[k];
        }
        // drain the last full block already staged in a[]
        uint4 q[8];
        #pragma unroll
        for (int k = 0; k < 8; ++k)
            q[k] = *(const uint4*)(srcB + (size_t)((unsigned)a[k].y | poff));
        #pragma unroll
        for (int k = 0; k < 8; ++k) {
            f32x2 v; v.x = __int_as_float(a[k].x); v.y = v.x;
            s[0] += v * bfpair(q[k].x);
            s[1] += v * bfpair(q[k].y);
            s[2] += v * bfpair(q[k].z);
            s[3] += v * bfpair(q[k].w);
        }
        e += 8;
    }
    // masked tail: one 8-wide block with clamped addresses, zeroed values
    if (e < end) {
        int2 a[8];
        #pragma unroll
        for (int k = 0; k < 8; ++k) {
            int idx = e + k;
            a[k] = sorted[idx < end ? idx : end - 1];
            if (idx >= end) a[k].x = 0;           // zero weight for pad slots
        }
        uint4 q[8];
        #pragma unroll
        for (int k = 0; k < 8; ++k)
            q[k] = *(const uint4*)(srcB + (size_t)((unsigned)a[k].y | poff));
        #pragma unroll
        for (int k = 0; k < 8; ++k) {
            f32x2 v; v.x = __int_as_float(a[k].x); v.y = v.x;
            s[0] += v * bfpair(q[k].x);
            s[1] += v * bfpair(q[k].y);
            s[2] += v * bfpair(q[k].z);
            s[3] += v * bfpair(q[k].w);
        }
    }
}

// Full SpMM over all N rows (degree-permuted order):
// dst_b(bf16) = w*A@src + (1-w)*sem. 8 equal-degree rows per wave.
__global__ void spmm_csr_full_kernel(const int2* __restrict__ sorted,
                                     const int2* __restrict__ row_ptr2,
                                     const int*  __restrict__ perm,
                                     const unsigned short* __restrict__ src,
                                     const float* __restrict__ symptom_emb,
                                     const float* __restrict__ herb_emb,
                                     const float* __restrict__ user_lw,
                                     const float* __restrict__ item_lw,
                                     int layer,
                                     unsigned short* __restrict__ dst_b) {
    int wid  = threadIdx.x >> 6;
    int lane = threadIdx.x & 63;
    int r    = lane >> 3;     // row within the wave's 8-row group
    int p    = lane & 7;      // dim oct 0..7 (dims 8p..8p+7)
    int slot = (blockIdx.x * (blockDim.x >> 6) + wid) * 8 + r;
    if (slot >= NN) return;
    int row  = perm[slot];
    int2 rp  = row_ptr2[row];

    f32x2 s[4];
    csr_row_sum8(sorted, (const char*)src, rp.x, rp.y, (unsigned)(p << 4), s);

    size_t o = ((size_t)row << 6) + ((size_t)p << 3);
    float wgt;
    const float* semp;
    if (row < U_N) {
        wgt = sigmoidf_(user_lw[layer]);
        semp = symptom_emb + o;
    } else {
        wgt = sigmoidf_(item_lw[layer]);
        semp = herb_emb + o - ((size_t)U_N << 6);
    }
    float4 sa = *(const float4*)semp;
    float4 sb = *(const float4*)(semp + 4);
    float om = 1.0f - wgt;
    uint4 ob;
    ob.x = pack2bf(wgt * s[0].x + om * sa.x, wgt * s[0].y + om * sa.y);
    ob.y = pack2bf(wgt * s[1].x + om * sa.z, wgt * s[1].y + om * sa.w);
    ob.z = pack2bf(wgt * s[2].x + om * sb.x, wgt * s[2].y + om * sb.y);
    ob.w = pack2bf(wgt * s[3].x + om * sb.z, wgt * s[3].y + om * sb.w);
    *(uint4*)(dst_b + o) = ob;
}

// Compact last-layer SpMM over the 2B pair rows, FUSED with the accumulator
// sum: writes su[pair_slot] = e0(recomputed fp32) + e1b + e2b + e3 to e3c.
// gamma then just dots e3c[b] with e3c[B+b].
__global__ void spmm_csr_compact_kernel(const int2* __restrict__ sorted,
                                        const int2* __restrict__ row_ptr2,
                                        const unsigned short* __restrict__ src,
                                        const float* __restrict__ user_emb,
                                        const float* __restrict__ item_emb,
                                        const float* __restrict__ symptom_emb,
                                        const float* __restrict__ herb_emb,
                                        const float* __restrict__ user_lw,
                                        const float* __restrict__ item_lw,
                                        int layer,
                                        const int* __restrict__ users,
                                        const int* __restrict__ items,
                                        const unsigned short* __restrict__ e1b,
                                        const unsigned short* __restrict__ e2b,
                                        float* __restrict__ e3c,
                                        int B) {
    int wid  = threadIdx.x >> 6;
    int lane = threadIdx.x & 63;
    int r    = lane >> 3;
    int p    = lane & 7;
    int b    = (blockIdx.x * (blockDim.x >> 6) + wid) * 8 + r;
    if (b >= 2 * B) return;
    int row = (b < B) ? users[b] : (items[b - B] + U_N);
    int2 rp = row_ptr2[row];

    f32x2 s[4];
    csr_row_sum8(sorted, (const char*)src, rp.x, rp.y, (unsigned)(p << 4), s);

    size_t orow = ((size_t)row << 6) + ((size_t)p << 3);
    float wgt, w0;
    const float* semp;
    const float* embp;
    if (row < U_N) {
        wgt = sigmoidf_(user_lw[layer]);
        w0  = sigmoidf_(user_lw[0]);
        semp = symptom_emb + orow;
        embp = user_emb + orow;
    } else {
        size_t ol = orow - ((size_t)U_N << 6);
        wgt = sigmoidf_(item_lw[layer]);
        w0  = sigmoidf_(item_lw[0]);
        semp = herb_emb + ol;
        embp = item_emb + ol;
    }
    float4 sa = *(const float4*)semp;
    float4 sb = *(const float4*)(semp + 4);
    float4 ea = *(const float4*)embp;
    float4 eb = *(const float4*)(embp + 4);
    uint4 q1 = ((const uint4*)e1b)[((size_t)row << 3) + p];
    uint4 q2 = ((const uint4*)e2b)[((size_t)row << 3) + p];
    float om = 1.0f - wgt, om0 = 1.0f - w0;
    // su_j = e0_j + e1_j + e2_j + e3_j
    float4 ra, rb;
    ra.x = (w0 * ea.x + om0 * sa.x) + bf_lo(q1.x) + bf_lo(q2.x)
         + (wgt * s[0].x + om * sa.x);
    ra.y = (w0 * ea.y + om0 * sa.y) + bf_hi(q1.x) + bf_hi(q2.x)
         + (wgt * s[0].y + om * sa.y);
    ra.z = (w0 * ea.z + om0 * sa.z) + bf_lo(q1.y) + bf_lo(q2.y)
         + (wgt * s[1].x + om * sa.z);
    ra.w = (w0 * ea.w + om0 * sa.w) + bf_hi(q1.y) + bf_hi(q2.y)
         + (wgt * s[1].y + om * sa.w);
    rb.x = (w0 * eb.x + om0 * sb.x) + bf_lo(q1.z) + bf_lo(q2.z)
         + (wgt * s[2].x + om * sb.x);
    rb.y = (w0 * eb.y + om0 * sb.y) + bf_hi(q1.z) + bf_hi(q2.z)
         + (wgt * s[2].y + om * sb.y);
    rb.z = (w0 * eb.z + om0 * sb.z) + bf_lo(q1.w) + bf_lo(q2.w)
         + (wgt * s[3].x + om * sb.z);
    rb.w = (w0 * eb.w + om0 * sb.w) + bf_hi(q1.w) + bf_hi(q2.w)
         + (wgt * s[3].y + om * sb.w);
    float* op = e3c + ((size_t)b << 6) + ((size_t)p << 3);
    *(float4*)op = ra;
    *(float4*)(op + 4) = rb;
}

// ---------------------------------------------------------------------------
// Readout: one wave per (user,item) pair; gamma = dot(su, si) / 16 where
// su/si are the pre-summed accumulator rows in e3c.
// ---------------------------------------------------------------------------
__global__ void gamma_kernel(const float* __restrict__ e3c,
                             float* __restrict__ out,
                             int B) {
    int gtid = blockIdx.x * blockDim.x + threadIdx.x;
    int wid  = gtid >> 6;
    int lane = threadIdx.x & 63;
    if (wid >= B) return;
    float su = e3c[((size_t)wid << 6) | lane];
    float si = e3c[((size_t)(B + wid) << 6) | lane];
    float pr = su * si;
    #pragma unroll
    for (int off = 32; off > 0; off >>= 1)
        pr += __shfl_down(pr, off, 64);
    if (lane == 0) out[wid] = pr * (1.0f / 16.0f);
}

// ---------------------------------------------------------------------------
// Fallback (round-1 atomic scatter) kernels, used only if ws too small
// ---------------------------------------------------------------------------
__global__ void fuse0_kernel(const float* __restrict__ user_emb,
                             const float* __restrict__ item_emb,
                             const float* __restrict__ symptom_emb,
                             const float* __restrict__ herb_emb,
                             const float* __restrict__ user_lw,
                             const float* __restrict__ item_lw,
                             float* __restrict__ bufA,
                             float* __restrict__ acc,
                             float* __restrict__ bufB) {
    long long idx = (long long)blockIdx.x * blockDim.x + threadIdx.x;
    if (idx >= ND4) return;
    float a0 = sigmoidf_(user_lw[0]);
    float b0 = sigmoidf_(item_lw[0]);
    float4 e, s;
    float w;
    if (idx < UD4) {
        e = ((const float4*)user_emb)[idx];
        s = ((const float4*)symptom_emb)[idx];
        w = a0;
    } else {
        long long j = idx - UD4;
        e = ((const float4*)item_emb)[j];
        s = ((const float4*)herb_emb)[j];
        w = b0;
    }
    float4 r;
    r.x = w * e.x + (1.0f - w) * s.x;
    r.y = w * e.y + (1.0f - w) * s.y;
    r.z = w * e.z + (1.0f - w) * s.z;
    r.w = w * e.w + (1.0f - w) * s.w;
    ((float4*)bufA)[idx] = r;
    ((float4*)acc)[idx]  = r;
    float4 z; z.x = z.y = z.z = z.w = 0.0f;
    ((float4*)bufB)[idx] = z;
}

__global__ void spmm_scatter_kernel(const float* __restrict__ edge_val,
                                    const int*   __restrict__ edge_row,
                                    const int*   __restrict__ edge_col,
                                    const float* __restrict__ src,
                                    float*       __restrict__ dst,
                                    long long total) {
    long long idx = (long long)blockIdx.x * blockDim.x + threadIdx.x;
    if (idx >= total) return;
    long long e = idx >> 4;
    int       q = (int)(idx & 15);
    int r = edge_row[e];
    int c = edge_col[e];
    float v = edge_val[e];
    float4 x = *(const float4*)(src + (long long)c * D + q * 4);
    float* d = dst + (long long)r * D + q * 4;
    atomicAdd(d + 0, v * x.x);
    atomicAdd(d + 1, v * x.y);
    atomicAdd(d + 2, v * x.z);
    atomicAdd(d + 3, v * x.w);
}

__global__ void fuse_layer_kernel(const float* __restrict__ symptom_emb,
                                  const float* __restrict__ herb_emb,
                                  const float* __restrict__ user_lw,
                                  const float* __restrict__ item_lw,
                                  int layer,
                                  float* __restrict__ bufA,
                                  float* __restrict__ bufB,
                                  float* __restrict__ acc) {
    long long idx = (long long)blockIdx.x * blockDim.x + threadIdx.x;
    if (idx >= ND4) return;
    float a = sigmoidf_(user_lw[layer]);
    float b = sigmoidf_(item_lw[layer]);
    float4 m = ((float4*)bufB)[idx];
    float4 z; z.x = z.y = z.z = z.w = 0.0f;
    ((float4*)bufB)[idx] = z;
    float4 s;
    float w;
    if (idx < UD4) {
        s = ((const float4*)symptom_emb)[idx];
        w = a;
    } else {
        s = ((const float4*)herb_emb)[idx - UD4];
        w = b;
    }
    float4 r;
    r.x = w * m.x + (1.0f - w) * s.x;
    r.y = w * m.y + (1.0f - w) * s.y;
    r.z = w * m.z + (1.0f - w) * s.z;
    r.w = w * m.w + (1.0f - w) * s.w;
    ((float4*)bufA)[idx] = r;
    float4 ac = ((float4*)acc)[idx];
    ac.x += r.x; ac.y += r.y; ac.z += r.z; ac.w += r.w;
    ((float4*)acc)[idx] = ac;
}

__global__ void gamma_acc_kernel(const float* __restrict__ acc,
                                 const int* __restrict__ users,
                                 const int* __restrict__ items,
                                 float* __restrict__ out,
                                 int B) {
    int gtid = blockIdx.x * blockDim.x + threadIdx.x;
    int wid  = gtid >> 6;
    int lane = threadIdx.x & 63;
    if (wid >= B) return;
    int u  = users[wid];
    int it = items[wid];
    float su = acc[(long long)u * D + lane];
    float si = acc[((long long)(U_N + it)) * D + lane];
    float p = su * si;
    #pragma unroll
    for (int off = 32; off > 0; off >>= 1)
        p += __shfl_down(p, off, 64);
    if (lane == 0) out[wid] = p * (1.0f / 16.0f);
}

extern "C" void kernel_launch(void* const* d_in, const int* in_sizes, int n_in,
                              void* d_out, int out_size, void* d_ws, size_t ws_size,
                              hipStream_t stream) {
    const float* user_emb    = (const float*)d_in[0];
    const float* item_emb    = (const float*)d_in[1];
    const float* symptom_emb = (const float*)d_in[2];
    const float* herb_emb    = (const float*)d_in[3];
    const float* user_lw     = (const float*)d_in[4];
    const float* item_lw     = (const float*)d_in[5];
    const float* edge_val    = (const float*)d_in[6];
    const int*   edge_row    = (const int*)d_in[7];
    const int*   edge_col    = (const int*)d_in[8];
    const int*   users       = (const int*)d_in[9];
    const int*   items       = (const int*)d_in[10];
    float* out = (float*)d_out;

    const int E = in_sizes[6];
    const int B = in_sizes[9];
    const int TPB = 256;

    // Fused-scatter geometry: chunk <= KSTAGE*1024 so register staging fits.
    int ablk2 = (E + 12499) / 12500;              // 512 for E=6.4M
    int chunk = (E + ablk2 - 1) / ablk2;          // <= 12500 <= SCHUNK_MAX
    // Bucket slab capacity: mean + 6.25% + 1024 (~11+ sigma for uniform rows)
    int cap = E / NBKT + E / NBKT / 16 + 1024;
    size_t slab_bytes = (size_t)NBKT * cap * 8;

    // ---- fast-path workspace layout (256B-aligned carve) ----
    size_t off = 0;
    auto carve = [&](size_t bytes) -> char* {
        char* p = (char*)d_ws + off;
        off += (bytes + 255) & ~(size_t)255;
        return p;
    };
    unsigned short* e0b     = (unsigned short*)carve(NDLL * 2);
    unsigned short* e1b     = (unsigned short*)carve(NDLL * 2);
    int2*           binned  = (int2*)carve(slab_bytes);
    int2*           sorted  = (int2*)carve(slab_bytes);
    int2*           row_ptr2= (int2*)carve((size_t)NN * 8);
    int*            cursor  = (int*)carve((size_t)NBKT * 4);
    int*            perm    = (int*)carve((size_t)NN * 4);
    int*            dhist   = (int*)carve((size_t)DBINS * 4);
    int*            dcur    = (int*)carve((size_t)DBINS * 4);
    const size_t fast_bytes = off;
    unsigned short* e2b = e0b;            // alias (e0b dead after spmm1)
    float*          e3c = (float*)binned; // alias (binned dead after pass B)

    if (ws_size >= fast_bytes && slab_bytes >= (size_t)2 * B * D * 4
        && chunk <= SCHUNK_MAX) {
        // ================= fast path: bucket-sorted CSR + bf16 gather =======
        int fb = (int)((ND4 + TPB - 1) / TPB);
        fuse0_bf16_kernel<<<fb, TPB, 0, stream>>>(user_emb, item_emb, symptom_emb,
                                                  herb_emb, user_lw, item_lw, e0b);

        init_cursor_kernel<<<1, 256, 0, stream>>>(cursor, cap);
        fused_scatter_kernel<<<ablk2, 1024, 0, stream>>>(edge_val, edge_row,
                                                         edge_col, cursor,
                                                         binned, E, chunk);
        bucket_to_csr_kernel<<<NBKT, BKT_W, 0, stream>>>(binned, cursor,
                                                         row_ptr2, sorted, cap);

        // Degree-balanced (descending) row permutation
        int pblocks = (NN + 1023) / 1024;
        zero_hist_kernel<<<1, DBINS, 0, stream>>>(dhist);
        deg_hist_kernel<<<pblocks, 1024, 0, stream>>>(row_ptr2, dhist);
        scan_hist_kernel<<<1, DBINS, 0, stream>>>(dhist, dcur);
        perm_scatter_kernel<<<pblocks, 1024, 0, stream>>>(row_ptr2, dcur, perm);

        // 8 rows per wave, 4 waves per block -> 32 rows/block
        int sblocks = (NN + 31) / 32;
        spmm_csr_full_kernel<<<sblocks, TPB, 0, stream>>>(
            sorted, row_ptr2, perm, e0b, symptom_emb, herb_emb,
            user_lw, item_lw, 1, e1b);
        spmm_csr_full_kernel<<<sblocks, TPB, 0, stream>>>(
            sorted, row_ptr2, perm, e1b, symptom_emb, herb_emb,
            user_lw, item_lw, 2, e2b);
        int cblocks = (2 * B + 31) / 32;
        spmm_csr_compact_kernel<<<cblocks, TPB, 0, stream>>>(
            sorted, row_ptr2, e2b, user_emb, item_emb, symptom_emb, herb_emb,
            user_lw, item_lw, 3, users, items, e1b, e2b, e3c, B);

        int gblocks = (B * 64 + TPB - 1) / TPB;
        gamma_kernel<<<gblocks, TPB, 0, stream>>>(e3c, out, B);
    } else {
        // ================= fallback: atomic scatter =========================
        float* bufA = (float*)d_ws;
        float* bufB = bufA + NDLL;
        float* acc2 = bufB + NDLL;

        int fb = (int)((ND4 + TPB - 1) / TPB);
        fuse0_kernel<<<fb, TPB, 0, stream>>>(user_emb, item_emb, symptom_emb,
                                             herb_emb, user_lw, item_lw,
                                             bufA, acc2, bufB);
        for (int layer = 1; layer <= NL; ++layer) {
            long long total = (long long)E * 16;
            int blocks = (int)((total + TPB - 1) / TPB);
            spmm_scatter_kernel<<<blocks, TPB, 0, stream>>>(edge_val, edge_row,
                                                            edge_col, bufA, bufB,
                                                            total);
            int fblocks = (int)((ND4 + TPB - 1) / TPB);
            fuse_layer_kernel<<<fblocks, TPB, 0, stream>>>(symptom_emb, herb_emb,
                                                           user_lw, item_lw, layer,
                                                           bufA, bufB, acc2);
        }
        int gblocks = (B * 64 + TPB - 1) / TPB;
        gamma_acc_kernel<<<gblocks, TPB, 0, stream>>>(acc2, users, items, out, B);
    }
}

// Round 5
// 556.411 us; speedup vs baseline: 1.0578x; 1.0578x over previous
//
#include <hip/hip_runtime.h>

// Problem constants (match reference)
constexpr int U_N = 100000;   // users
constexpr int I_N = 100000;   // items
constexpr int D   = 64;       // latent dim
constexpr int NL  = 3;        // layers
constexpr int NN  = U_N + I_N;              // 200000 nodes
constexpr long long NDLL = (long long)NN * D;
constexpr long long ND4  = NDLL / 4;
constexpr long long UD4  = (long long)U_N * D / 4;

// Bucket sort parameters: bucket = row >> 8  (256 rows per bucket).
// R5: shrunk from 1024 to 256 rows so bucket_to_csr gets 782 blocks (3x CU
// parallelism) and a whole bucket slab fits in LDS for coalesced output.
constexpr int BKT_SHIFT = 8;
constexpr int BKT_W     = 256;                      // rows per bucket
constexpr int NBKT      = (NN + BKT_W - 1) / BKT_W; // 782
constexpr int CAP_MAX   = 9216;                     // LDS stage bound (edges)
// Fused scatter: 1024-thread blocks, <=13 staged edges per thread.
constexpr int KSTAGE    = 13;
constexpr int SCHUNK_MAX = KSTAGE * 1024;           // 13312

typedef float f32x2 __attribute__((ext_vector_type(2)));

__device__ __forceinline__ float sigmoidf_(float x) {
    return 1.0f / (1.0f + expf(-x));
}

__device__ __forceinline__ float bf_lo(unsigned int u) {
    return __uint_as_float(u << 16);
}
__device__ __forceinline__ float bf_hi(unsigned int u) {
    return __uint_as_float(u & 0xFFFF0000u);
}
// unpack a packed bf16 pair into a float2 (dims 2k, 2k+1)
__device__ __forceinline__ f32x2 bfpair(unsigned int u) {
    f32x2 r;
    r.x = __uint_as_float(u << 16);
    r.y = __uint_as_float(u & 0xFFFF0000u);
    return r;
}
__device__ __forceinline__ unsigned short f2bf(float f) {
    unsigned int u = __float_as_uint(f);
    u += 0x7FFFu + ((u >> 16) & 1u);   // round-to-nearest-even
    return (unsigned short)(u >> 16);
}
__device__ __forceinline__ unsigned int pack2bf(float lo, float hi) {
    return (unsigned int)f2bf(lo) | ((unsigned int)f2bf(hi) << 16);
}

// ---------------------------------------------------------------------------
// Layer-0 fusion: e0b(bf16) = fused emb (gather source for layer 1).
// ---------------------------------------------------------------------------
__global__ void fuse0_bf16_kernel(const float* __restrict__ user_emb,
                                  const float* __restrict__ item_emb,
                                  const float* __restrict__ symptom_emb,
                                  const float* __restrict__ herb_emb,
                                  const float* __restrict__ user_lw,
                                  const float* __restrict__ item_lw,
                                  unsigned short* __restrict__ e0b) {
    long long idx = (long long)blockIdx.x * blockDim.x + threadIdx.x;
    if (idx >= ND4) return;
    float a0 = sigmoidf_(user_lw[0]);
    float b0 = sigmoidf_(item_lw[0]);
    float4 e, s;
    float w;
    if (idx < UD4) {
        e = ((const float4*)user_emb)[idx];
        s = ((const float4*)symptom_emb)[idx];
        w = a0;
    } else {
        long long j = idx - UD4;
        e = ((const float4*)item_emb)[j];
        s = ((const float4*)herb_emb)[j];
        w = b0;
    }
    ushort4 rb;
    rb.x = f2bf(w * e.x + (1.0f - w) * s.x);
    rb.y = f2bf(w * e.y + (1.0f - w) * s.y);
    rb.z = f2bf(w * e.z + (1.0f - w) * s.z);
    rb.w = f2bf(w * e.w + (1.0f - w) * s.w);
    ((ushort4*)e0b)[idx] = rb;
}

// ---------------------------------------------------------------------------
// CSR build, slab layout: bucket b owns slab [b*cap, b*cap + cnt_b) in
// binned. Cursor init -> fused count+scatter -> per-bucket LDS-staged CSR.
// ---------------------------------------------------------------------------
__global__ void init_cursor_kernel(int* __restrict__ cursor, int cap) {
    int i = blockIdx.x * blockDim.x + threadIdx.x;
    if (i < NBKT) cursor[i] = i * cap;
}

// Fused hist+reserve+scatter: reads (val,row,col) exactly once, stages them
// in registers (statically indexed via full unroll), counts into LDS hist,
// reserves one global-atomic slab range per (block,bucket), scatters.
__global__ void fused_scatter_kernel(const float* __restrict__ edge_val,
                                     const int*   __restrict__ edge_row,
                                     const int*   __restrict__ edge_col,
                                     int* __restrict__ cursor,
                                     int2* __restrict__ binned,
                                     int E, int chunk) {
    __shared__ int h[NBKT];
    int tid = threadIdx.x;
    if (tid < NBKT) h[tid] = 0;
    __syncthreads();
    int s_ = blockIdx.x * chunk;
    int eend = min(E, s_ + chunk);
    int rr[KSTAGE];
    int cc[KSTAGE];
    float vv[KSTAGE];
    #pragma unroll
    for (int k = 0; k < KSTAGE; ++k) {
        int e = s_ + tid + k * 1024;
        bool ok = e < eend;
        rr[k] = ok ? edge_row[e] : -1;
        cc[k] = ok ? edge_col[e] : 0;
        vv[k] = ok ? edge_val[e] : 0.0f;
        if (ok) atomicAdd(&h[rr[k] >> BKT_SHIFT], 1);
    }
    __syncthreads();
    if (tid < NBKT) {
        int c = h[tid];
        if (c) h[tid] = atomicAdd(&cursor[tid], c);
    }
    __syncthreads();
    #pragma unroll
    for (int k = 0; k < KSTAGE; ++k) {
        if (rr[k] >= 0) {
            int b = rr[k] >> BKT_SHIFT;
            int pos = atomicAdd(&h[b], 1);
            binned[pos] = make_int2(__float_as_int(vv[k]),
                                    cc[k] | ((rr[k] & (BKT_W - 1)) << 18));
        }
    }
}

// Per-bucket CSR, fully LDS-staged: load the bucket slab into LDS, count +
// scan + inverse-permutation all in LDS, then write row_ptr2 and a fully
// COALESCED row-sorted slab (consecutive threads -> consecutive slots).
// sorted.y stores col<<7 (byte offset of 128 B source row) so the spmm
// gather address is a single OR with the lane's oct offset.
__global__ void bucket_to_csr_kernel(const int2* __restrict__ binned,
                                     const int*  __restrict__ cursor,
                                     int2* __restrict__ row_ptr2,
                                     int2* __restrict__ sorted, int cap) {
    __shared__ int2 eds[CAP_MAX];
    __shared__ int  inv[CAP_MAX];
    __shared__ int  rc[BKT_W];
    __shared__ int  sm[BKT_W];
    int b = blockIdx.x;
    int start = b * cap;
    int cnt   = cursor[b] - start;           // bucket edge count
    if (cnt > CAP_MAX) cnt = CAP_MAX;        // safety clamp (shouldn't happen)
    int tid = threadIdx.x;                   // blockDim.x == 1024
    if (tid < BKT_W) rc[tid] = 0;
    __syncthreads();
    for (int i = tid; i < cnt; i += 1024) {
        int2 a = binned[start + i];
        eds[i] = a;
        atomicAdd(&rc[(unsigned)a.y >> 18], 1);
    }
    __syncthreads();
    int x = 0;
    if (tid < BKT_W) { x = rc[tid]; sm[tid] = x; }
    __syncthreads();
    for (int off = 1; off < BKT_W; off <<= 1) {
        int t = (tid >= off && tid < BKT_W) ? sm[tid - off] : 0;
        __syncthreads();
        if (tid < BKT_W) sm[tid] += t;
        __syncthreads();
    }
    if (tid < BKT_W) {
        int excl = sm[tid] - x;
        int gidx = (b << BKT_SHIFT) + tid;
        if (gidx < NN)
            row_ptr2[gidx] = make_int2(start + excl, start + excl + x);
        rc[tid] = excl;
    }
    __syncthreads();
    for (int i = tid; i < cnt; i += 1024) {
        int rl  = (unsigned)eds[i].y >> 18;
        int pos = atomicAdd(&rc[rl], 1);
        inv[pos] = i;                         // LDS scatter (cheap)
    }
    __syncthreads();
    for (int t_ = tid; t_ < cnt; t_ += 1024) {
        int2 a = eds[inv[t_]];                // LDS random read (cheap)
        sorted[start + t_] = make_int2(a.x, (a.y & 0x3FFFF) << 7);  // coalesced
    }
}

// ---------------------------------------------------------------------------
// Core CSR row accumulation, 8-rows-per-wave layout: lane = (r,p):
// r = row-in-group (8), p = dim oct (8). Each 8-lane group sequentially
// accumulates its own row (no cross-lane reduce).
// Unroll-8 + software pipeline: gathers for block i overlap the sorted
// loads for block i+1. Tail = single masked 8-wide block.
// sorted.y is pre-shifted col<<7; gather byte addr = y | (p<<4).
// ---------------------------------------------------------------------------
__device__ __forceinline__ void csr_row_sum8(const int2* __restrict__ sorted,
                                             const char* __restrict__ srcB,
                                             int start, int end, unsigned poff,
                                             f32x2 s[4]) {
    #pragma unroll
    for (int j = 0; j < 4; ++j) s[j] = (f32x2){0.f, 0.f};
    int e = start;
    if (e + 8 <= end) {
        int2 a[8];
        #pragma unroll
        for (int k = 0; k < 8; ++k) a[k] = sorted[e + k];
        // steady state: gathers(i) || sorted-loads(i+1)
        for (; e + 16 <= end; e += 8) {
            uint4 q[8];
            #pragma unroll
            for (int k = 0; k < 8; ++k)
                q[k] = *(const uint4*)(srcB + (size_t)((unsigned)a[k].y | poff));
            int2 an[8];
            #pragma unroll
            for (int k = 0; k < 8; ++k) an[k] = sorted[e + 8 + k];
            #pragma unroll
            for (int k = 0; k < 8; ++k) {
                f32x2 v; v.x = __int_as_float(a[k].x); v.y = v.x;
                s[0] += v * bfpair(q[k].x);
                s[1] += v * bfpair(q[k].y);
                s[2] += v * bfpair(q[k].z);
                s[3] += v * bfpair(q[k].w);
            }
            #pragma unroll
            for (int k = 0; k < 8; ++k) a[k] = an[k];
        }
        // drain the last full block already staged in a[]
        uint4 q[8];
        #pragma unroll
        for (int k = 0; k < 8; ++k)
            q[k] = *(const uint4*)(srcB + (size_t)((unsigned)a[k].y | poff));
        #pragma unroll
        for (int k = 0; k < 8; ++k) {
            f32x2 v; v.x = __int_as_float(a[k].x); v.y = v.x;
            s[0] += v * bfpair(q[k].x);
            s[1] += v * bfpair(q[k].y);
            s[2] += v * bfpair(q[k].z);
            s[3] += v * bfpair(q[k].w);
        }
        e += 8;
    }
    // masked tail: one 8-wide block with clamped addresses, zeroed values
    if (e < end) {
        int2 a[8];
        #pragma unroll
        for (int k = 0; k < 8; ++k) {
            int idx = e + k;
            a[k] = sorted[idx < end ? idx : end - 1];
            if (idx >= end) a[k].x = 0;           // zero weight for pad slots
        }
        uint4 q[8];
        #pragma unroll
        for (int k = 0; k < 8; ++k)
            q[k] = *(const uint4*)(srcB + (size_t)((unsigned)a[k].y | poff));
        #pragma unroll
        for (int k = 0; k < 8; ++k) {
            f32x2 v; v.x = __int_as_float(a[k].x); v.y = v.x;
            s[0] += v * bfpair(q[k].x);
            s[1] += v * bfpair(q[k].y);
            s[2] += v * bfpair(q[k].z);
            s[3] += v * bfpair(q[k].w);
        }
    }
}

// Full SpMM over all N rows: dst_b(bf16) = w*A@src + (1-w)*sem
// 8 rows per wave; all 64 lanes active in epilogue; 1 KB coalesced store/wave.
__global__ void spmm_csr_full_kernel(const int2* __restrict__ sorted,
                                     const int2* __restrict__ row_ptr2,
                                     const unsigned short* __restrict__ src,
                                     const float* __restrict__ symptom_emb,
                                     const float* __restrict__ herb_emb,
                                     const float* __restrict__ user_lw,
                                     const float* __restrict__ item_lw,
                                     int layer,
                                     unsigned short* __restrict__ dst_b) {
    int wid  = threadIdx.x >> 6;
    int lane = threadIdx.x & 63;
    int r    = lane >> 3;     // row within the wave's 8-row group
    int p    = lane & 7;      // dim oct 0..7 (dims 8p..8p+7)
    int row  = (blockIdx.x * (blockDim.x >> 6) + wid) * 8 + r;
    if (row >= NN) return;
    int2 rp = row_ptr2[row];

    f32x2 s[4];
    csr_row_sum8(sorted, (const char*)src, rp.x, rp.y, (unsigned)(p << 4), s);

    size_t o = ((size_t)row << 6) + ((size_t)p << 3);
    float wgt;
    const float* semp;
    if (row < U_N) {
        wgt = sigmoidf_(user_lw[layer]);
        semp = symptom_emb + o;
    } else {
        wgt = sigmoidf_(item_lw[layer]);
        semp = herb_emb + o - ((size_t)U_N << 6);
    }
    float4 sa = *(const float4*)semp;
    float4 sb = *(const float4*)(semp + 4);
    float om = 1.0f - wgt;
    uint4 ob;
    ob.x = pack2bf(wgt * s[0].x + om * sa.x, wgt * s[0].y + om * sa.y);
    ob.y = pack2bf(wgt * s[1].x + om * sa.z, wgt * s[1].y + om * sa.w);
    ob.z = pack2bf(wgt * s[2].x + om * sb.x, wgt * s[2].y + om * sb.y);
    ob.w = pack2bf(wgt * s[3].x + om * sb.z, wgt * s[3].y + om * sb.w);
    *(uint4*)(dst_b + o) = ob;
}

// Compact last-layer SpMM over the 2B pair rows, FUSED with the accumulator
// sum: writes su[pair_slot] = e0(recomputed fp32) + e1b + e2b + e3 to e3c.
// gamma then just dots e3c[b] with e3c[B+b].
__global__ void spmm_csr_compact_kernel(const int2* __restrict__ sorted,
                                        const int2* __restrict__ row_ptr2,
                                        const unsigned short* __restrict__ src,
                                        const float* __restrict__ user_emb,
                                        const float* __restrict__ item_emb,
                                        const float* __restrict__ symptom_emb,
                                        const float* __restrict__ herb_emb,
                                        const float* __restrict__ user_lw,
                                        const float* __restrict__ item_lw,
                                        int layer,
                                        const int* __restrict__ users,
                                        const int* __restrict__ items,
                                        const unsigned short* __restrict__ e1b,
                                        const unsigned short* __restrict__ e2b,
                                        float* __restrict__ e3c,
                                        int B) {
    int wid  = threadIdx.x >> 6;
    int lane = threadIdx.x & 63;
    int r    = lane >> 3;
    int p    = lane & 7;
    int b    = (blockIdx.x * (blockDim.x >> 6) + wid) * 8 + r;
    if (b >= 2 * B) return;
    int row = (b < B) ? users[b] : (items[b - B] + U_N);
    int2 rp = row_ptr2[row];

    f32x2 s[4];
    csr_row_sum8(sorted, (const char*)src, rp.x, rp.y, (unsigned)(p << 4), s);

    size_t orow = ((size_t)row << 6) + ((size_t)p << 3);
    float wgt, w0;
    const float* semp;
    const float* embp;
    if (row < U_N) {
        wgt = sigmoidf_(user_lw[layer]);
        w0  = sigmoidf_(user_lw[0]);
        semp = symptom_emb + orow;
        embp = user_emb + orow;
    } else {
        size_t ol = orow - ((size_t)U_N << 6);
        wgt = sigmoidf_(item_lw[layer]);
        w0  = sigmoidf_(item_lw[0]);
        semp = herb_emb + ol;
        embp = item_emb + ol;
    }
    float4 sa = *(const float4*)semp;
    float4 sb = *(const float4*)(semp + 4);
    float4 ea = *(const float4*)embp;
    float4 eb = *(const float4*)(embp + 4);
    uint4 q1 = ((const uint4*)e1b)[((size_t)row << 3) + p];
    uint4 q2 = ((const uint4*)e2b)[((size_t)row << 3) + p];
    float om = 1.0f - wgt, om0 = 1.0f - w0;
    // su_j = e0_j + e1_j + e2_j + e3_j
    float4 ra, rb;
    ra.x = (w0 * ea.x + om0 * sa.x) + bf_lo(q1.x) + bf_lo(q2.x)
         + (wgt * s[0].x + om * sa.x);
    ra.y = (w0 * ea.y + om0 * sa.y) + bf_hi(q1.x) + bf_hi(q2.x)
         + (wgt * s[0].y + om * sa.y);
    ra.z = (w0 * ea.z + om0 * sa.z) + bf_lo(q1.y) + bf_lo(q2.y)
         + (wgt * s[1].x + om * sa.z);
    ra.w = (w0 * ea.w + om0 * sa.w) + bf_hi(q1.y) + bf_hi(q2.y)
         + (wgt * s[1].y + om * sa.w);
    rb.x = (w0 * eb.x + om0 * sb.x) + bf_lo(q1.z) + bf_lo(q2.z)
         + (wgt * s[2].x + om * sb.x);
    rb.y = (w0 * eb.y + om0 * sb.y) + bf_hi(q1.z) + bf_hi(q2.z)
         + (wgt * s[2].y + om * sb.y);
    rb.z = (w0 * eb.z + om0 * sb.z) + bf_lo(q1.w) + bf_lo(q2.w)
         + (wgt * s[3].x + om * sb.z);
    rb.w = (w0 * eb.w + om0 * sb.w) + bf_hi(q1.w) + bf_hi(q2.w)
         + (wgt * s[3].y + om * sb.w);
    float* op = e3c + ((size_t)b << 6) + ((size_t)p << 3);
    *(float4*)op = ra;
    *(float4*)(op + 4) = rb;
}

// ---------------------------------------------------------------------------
// Readout: one wave per (user,item) pair; gamma = dot(su, si) / 16 where
// su/si are the pre-summed accumulator rows in e3c.
// ---------------------------------------------------------------------------
__global__ void gamma_kernel(const float* __restrict__ e3c,
                             float* __restrict__ out,
                             int B) {
    int gtid = blockIdx.x * blockDim.x + threadIdx.x;
    int wid  = gtid >> 6;
    int lane = threadIdx.x & 63;
    if (wid >= B) return;
    float su = e3c[((size_t)wid << 6) | lane];
    float si = e3c[((size_t)(B + wid) << 6) | lane];
    float pr = su * si;
    #pragma unroll
    for (int off = 32; off > 0; off >>= 1)
        pr += __shfl_down(pr, off, 64);
    if (lane == 0) out[wid] = pr * (1.0f / 16.0f);
}

// ---------------------------------------------------------------------------
// Fallback (round-1 atomic scatter) kernels, used only if ws too small
// ---------------------------------------------------------------------------
__global__ void fuse0_kernel(const float* __restrict__ user_emb,
                             const float* __restrict__ item_emb,
                             const float* __restrict__ symptom_emb,
                             const float* __restrict__ herb_emb,
                             const float* __restrict__ user_lw,
                             const float* __restrict__ item_lw,
                             float* __restrict__ bufA,
                             float* __restrict__ acc,
                             float* __restrict__ bufB) {
    long long idx = (long long)blockIdx.x * blockDim.x + threadIdx.x;
    if (idx >= ND4) return;
    float a0 = sigmoidf_(user_lw[0]);
    float b0 = sigmoidf_(item_lw[0]);
    float4 e, s;
    float w;
    if (idx < UD4) {
        e = ((const float4*)user_emb)[idx];
        s = ((const float4*)symptom_emb)[idx];
        w = a0;
    } else {
        long long j = idx - UD4;
        e = ((const float4*)item_emb)[j];
        s = ((const float4*)herb_emb)[j];
        w = b0;
    }
    float4 r;
    r.x = w * e.x + (1.0f - w) * s.x;
    r.y = w * e.y + (1.0f - w) * s.y;
    r.z = w * e.z + (1.0f - w) * s.z;
    r.w = w * e.w + (1.0f - w) * s.w;
    ((float4*)bufA)[idx] = r;
    ((float4*)acc)[idx]  = r;
    float4 z; z.x = z.y = z.z = z.w = 0.0f;
    ((float4*)bufB)[idx] = z;
}

__global__ void spmm_scatter_kernel(const float* __restrict__ edge_val,
                                    const int*   __restrict__ edge_row,
                                    const int*   __restrict__ edge_col,
                                    const float* __restrict__ src,
                                    float*       __restrict__ dst,
                                    long long total) {
    long long idx = (long long)blockIdx.x * blockDim.x + threadIdx.x;
    if (idx >= total) return;
    long long e = idx >> 4;
    int       q = (int)(idx & 15);
    int r = edge_row[e];
    int c = edge_col[e];
    float v = edge_val[e];
    float4 x = *(const float4*)(src + (long long)c * D + q * 4);
    float* d = dst + (long long)r * D + q * 4;
    atomicAdd(d + 0, v * x.x);
    atomicAdd(d + 1, v * x.y);
    atomicAdd(d + 2, v * x.z);
    atomicAdd(d + 3, v * x.w);
}

__global__ void fuse_layer_kernel(const float* __restrict__ symptom_emb,
                                  const float* __restrict__ herb_emb,
                                  const float* __restrict__ user_lw,
                                  const float* __restrict__ item_lw,
                                  int layer,
                                  float* __restrict__ bufA,
                                  float* __restrict__ bufB,
                                  float* __restrict__ acc) {
    long long idx = (long long)blockIdx.x * blockDim.x + threadIdx.x;
    if (idx >= ND4) return;
    float a = sigmoidf_(user_lw[layer]);
    float b = sigmoidf_(item_lw[layer]);
    float4 m = ((float4*)bufB)[idx];
    float4 z; z.x = z.y = z.z = z.w = 0.0f;
    ((float4*)bufB)[idx] = z;
    float4 s;
    float w;
    if (idx < UD4) {
        s = ((const float4*)symptom_emb)[idx];
        w = a;
    } else {
        s = ((const float4*)herb_emb)[idx - UD4];
        w = b;
    }
    float4 r;
    r.x = w * m.x + (1.0f - w) * s.x;
    r.y = w * m.y + (1.0f - w) * s.y;
    r.z = w * m.z + (1.0f - w) * s.z;
    r.w = w * m.w + (1.0f - w) * s.w;
    ((float4*)bufA)[idx] = r;
    float4 ac = ((float4*)acc)[idx];
    ac.x += r.x; ac.y += r.y; ac.z += r.z; ac.w += r.w;
    ((float4*)acc)[idx] = ac;
}

__global__ void gamma_acc_kernel(const float* __restrict__ acc,
                                 const int* __restrict__ users,
                                 const int* __restrict__ items,
                                 float* __restrict__ out,
                                 int B) {
    int gtid = blockIdx.x * blockDim.x + threadIdx.x;
    int wid  = gtid >> 6;
    int lane = threadIdx.x & 63;
    if (wid >= B) return;
    int u  = users[wid];
    int it = items[wid];
    float su = acc[(long long)u * D + lane];
    float si = acc[((long long)(U_N + it)) * D + lane];
    float p = su * si;
    #pragma unroll
    for (int off = 32; off > 0; off >>= 1)
        p += __shfl_down(p, off, 64);
    if (lane == 0) out[wid] = p * (1.0f / 16.0f);
}

extern "C" void kernel_launch(void* const* d_in, const int* in_sizes, int n_in,
                              void* d_out, int out_size, void* d_ws, size_t ws_size,
                              hipStream_t stream) {
    const float* user_emb    = (const float*)d_in[0];
    const float* item_emb    = (const float*)d_in[1];
    const float* symptom_emb = (const float*)d_in[2];
    const float* herb_emb    = (const float*)d_in[3];
    const float* user_lw     = (const float*)d_in[4];
    const float* item_lw     = (const float*)d_in[5];
    const float* edge_val    = (const float*)d_in[6];
    const int*   edge_row    = (const int*)d_in[7];
    const int*   edge_col    = (const int*)d_in[8];
    const int*   users       = (const int*)d_in[9];
    const int*   items       = (const int*)d_in[10];
    float* out = (float*)d_out;

    const int E = in_sizes[6];
    const int B = in_sizes[9];
    const int TPB = 256;

    // Fused-scatter geometry: chunk <= KSTAGE*1024 so register staging fits.
    int ablk2 = (E + 12499) / 12500;              // 512 for E=6.4M
    int chunk = (E + ablk2 - 1) / ablk2;          // <= 12500 <= SCHUNK_MAX
    // Bucket slab capacity: mean + ~3% + 512 (>8 sigma for uniform rows);
    // must stay <= CAP_MAX so a bucket fits the LDS stage in bucket_to_csr.
    int cap = E / NBKT + E / NBKT / 32 + 512;
    size_t slab_bytes = (size_t)NBKT * cap * 8;

    // ---- fast-path workspace layout (256B-aligned carve) ----
    size_t off = 0;
    auto carve = [&](size_t bytes) -> char* {
        char* p = (char*)d_ws + off;
        off += (bytes + 255) & ~(size_t)255;
        return p;
    };
    unsigned short* e0b     = (unsigned short*)carve(NDLL * 2);
    unsigned short* e1b     = (unsigned short*)carve(NDLL * 2);
    int2*           binned  = (int2*)carve(slab_bytes);
    int2*           sorted  = (int2*)carve(slab_bytes);
    int2*           row_ptr2= (int2*)carve((size_t)NN * 8);
    int*            cursor  = (int*)carve((size_t)NBKT * 4);
    const size_t fast_bytes = off;
    unsigned short* e2b = e0b;            // alias (e0b dead after spmm1)
    float*          e3c = (float*)binned; // alias (binned dead after pass B)

    if (ws_size >= fast_bytes && slab_bytes >= (size_t)2 * B * D * 4
        && chunk <= SCHUNK_MAX && cap <= CAP_MAX) {
        // ================= fast path: bucket-sorted CSR + bf16 gather =======
        int fb = (int)((ND4 + TPB - 1) / TPB);
        fuse0_bf16_kernel<<<fb, TPB, 0, stream>>>(user_emb, item_emb, symptom_emb,
                                                  herb_emb, user_lw, item_lw, e0b);

        init_cursor_kernel<<<(NBKT + 255) / 256, 256, 0, stream>>>(cursor, cap);
        fused_scatter_kernel<<<ablk2, 1024, 0, stream>>>(edge_val, edge_row,
                                                         edge_col, cursor,
                                                         binned, E, chunk);
        bucket_to_csr_kernel<<<NBKT, 1024, 0, stream>>>(binned, cursor,
                                                        row_ptr2, sorted, cap);

        // 8 rows per wave, 4 waves per block -> 32 rows/block
        int sblocks = (NN + 31) / 32;
        spmm_csr_full_kernel<<<sblocks, TPB, 0, stream>>>(
            sorted, row_ptr2, e0b, symptom_emb, herb_emb,
            user_lw, item_lw, 1, e1b);
        spmm_csr_full_kernel<<<sblocks, TPB, 0, stream>>>(
            sorted, row_ptr2, e1b, symptom_emb, herb_emb,
            user_lw, item_lw, 2, e2b);
        int cblocks = (2 * B + 31) / 32;
        spmm_csr_compact_kernel<<<cblocks, TPB, 0, stream>>>(
            sorted, row_ptr2, e2b, user_emb, item_emb, symptom_emb, herb_emb,
            user_lw, item_lw, 3, users, items, e1b, e2b, e3c, B);

        int gblocks = (B * 64 + TPB - 1) / TPB;
        gamma_kernel<<<gblocks, TPB, 0, stream>>>(e3c, out, B);
    } else {
        // ================= fallback: atomic scatter =========================
        float* bufA = (float*)d_ws;
        float* bufB = bufA + NDLL;
        float* acc2 = bufB + NDLL;

        int fb = (int)((ND4 + TPB - 1) / TPB);
        fuse0_kernel<<<fb, TPB, 0, stream>>>(user_emb, item_emb, symptom_emb,
                                             herb_emb, user_lw, item_lw,
                                             bufA, acc2, bufB);
        for (int layer = 1; layer <= NL; ++layer) {
            long long total = (long long)E * 16;
            int blocks = (int)((total + TPB - 1) / TPB);
            spmm_scatter_kernel<<<blocks, TPB, 0, stream>>>(edge_val, edge_row,
                                                            edge_col, bufA, bufB,
                                                            total);
            int fblocks = (int)((ND4 + TPB - 1) / TPB);
            fuse_layer_kernel<<<fblocks, TPB, 0, stream>>>(symptom_emb, herb_emb,
                                                           user_lw, item_lw, layer,
                                                           bufA, bufB, acc2);
        }
        int gblocks = (B * 64 + TPB - 1) / TPB;
        gamma_acc_kernel<<<gblocks, TPB, 0, stream>>>(acc2, users, items, out, B);
    }
}